// Round 3
// baseline (803.503 us; speedup 1.0000x reference)
//
#include <hip/hip_runtime.h>
#include <cstdint>
#include <cstddef>

typedef unsigned short u16;
using half8 = __attribute__((ext_vector_type(8))) _Float16;
using f32x4 = __attribute__((ext_vector_type(4))) float;
using f4    = __attribute__((ext_vector_type(4))) float;

#define B_    16
#define C_    256
#define H_    128
#define W_    128
#define C4_   64
#define COUT_ 256
#define HW_   (H_ * W_)

#define LDS_S1    264   // kernel1 slab [w][c]: 256 + 8 pad (octet-swizzled columns)
#define QK_S      72    // kernel2 Q/K [h][d]: 64 + 8 pad
#define P_S       136   // kernel2 P   [h][g]: 128 + 8 pad

__device__ __forceinline__ u16 f16_rn(float f) {
  _Float16 h = (_Float16)f;   // RN
  return __builtin_bit_cast(u16, h);
}

// ---------------------------------------------------------------------------
// Kernel 1: Q/K/V 1x1-conv projections (fp16 operands, fp32 accum).
// Block = (b, h) via XCD-chunk swizzle (h-adjacent blocks share an XCD so the
// scattered V stores merge in that XCD's L2).
// Slab [C][W] fp32 staged transposed to fp16 LDS [w][c] with octet swizzle:
//   element (w,c) lives at w*LDS_S1 + ((c>>3)^((w>>2)&7))*8 + (c&7)
// Staging: float4-pair loads (rows c,c+1) -> packed b32 writes (4-way max).
// ---------------------------------------------------------------------------
__device__ __forceinline__ void stage_slab(const float* __restrict__ src,
                                           u16* __restrict__ ldsT, int t) {
#pragma unroll 4
  for (int i = 0; i < 16; ++i) {
    int u  = i * 256 + t;
    int p  = u >> 5;            // c-pair index 0..127
    int w4 = (u & 31) * 4;
    const float* s0 = src + (size_t)(2 * p) * HW_ + w4;
    f4 va = *reinterpret_cast<const f4*>(s0);
    f4 vb = *reinterpret_cast<const f4*>(s0 + HW_);
    const int c = 2 * p;
#pragma unroll
    for (int j = 0; j < 4; ++j) {
      int w   = w4 + j;
      int oct = (c >> 3) ^ ((w >> 2) & 7);
      uint32_t pk = (uint32_t)f16_rn(va[j]) | ((uint32_t)f16_rn(vb[j]) << 16);
      *reinterpret_cast<uint32_t*>(&ldsT[w * LDS_S1 + oct * 8 + (c & 7)]) = pk;
    }
  }
}

__device__ __forceinline__ const half8* afrag(const u16* __restrict__ ldsT,
                                              int w16, int ks, int lg) {
  int oct = (ks * 4 + lg) ^ ((w16 >> 2) & 7);
  return reinterpret_cast<const half8*>(&ldsT[w16 * LDS_S1 + oct * 8]);
}

__device__ __forceinline__ half8 wfrag(const float* __restrict__ Wm,
                                       int row, int ks, int lg) {
  const f4* wp = reinterpret_cast<const f4*>(Wm + (size_t)row * C_ + ks * 32 + lg * 8);
  f4 a = wp[0], b = wp[1];
  half8 r;
#pragma unroll
  for (int i = 0; i < 4; ++i) { r[i] = (_Float16)a[i]; r[4 + i] = (_Float16)b[i]; }
  return r;
}

__device__ __forceinline__ void proj64(const u16* __restrict__ ldsT,
                                       const float* __restrict__ Wm,
                                       const float* __restrict__ bm,
                                       u16* __restrict__ dst,
                                       int b, int h, int wv, int col, int lg) {
  f32x4 zero = {0.f, 0.f, 0.f, 0.f};
  f32x4 acc[8];
#pragma unroll
  for (int i = 0; i < 8; ++i) acc[i] = zero;
#pragma unroll
  for (int ks = 0; ks < 8; ++ks) {
    half8 bfr = wfrag(Wm, wv * 16 + col, ks, lg);
#pragma unroll
    for (int wt = 0; wt < 8; ++wt) {
      const half8 afr = *afrag(ldsT, wt * 16 + col, ks, lg);
      acc[wt] = __builtin_amdgcn_mfma_f32_16x16x32_f16(afr, bfr, acc[wt], 0, 0, 0);
    }
  }
  const float bias = bm[wv * 16 + col];
#pragma unroll
  for (int wt = 0; wt < 8; ++wt)
#pragma unroll
    for (int r = 0; r < 4; ++r) {
      int w = wt * 16 + lg * 4 + r;
      dst[(((size_t)b * W_ + w) * H_ + h) * C4_ + wv * 16 + col] =
          f16_rn(acc[wt][r] + bias);
    }
}

__global__ void __launch_bounds__(256) qkv_kernel(
    const float* __restrict__ flow, const float* __restrict__ de_out,
    const float* __restrict__ Wq, const float* __restrict__ bq,
    const float* __restrict__ Wk, const float* __restrict__ bk,
    const float* __restrict__ Wv, const float* __restrict__ bv,
    u16* __restrict__ Qws, u16* __restrict__ Kws, u16* __restrict__ Vws) {
  __shared__ __align__(16) u16 ldsT[128 * LDS_S1];
  const int t    = threadIdx.x;
  const int bid  = blockIdx.x;
  const int sw   = (bid & 7) * 256 + (bid >> 3);  // bijective (2048 % 8 == 0)
  const int b    = sw >> 7;
  const int h    = sw & 127;
  const int lane = t & 63;
  const int wv   = t >> 6;
  const int col  = lane & 15;
  const int lg   = lane >> 4;

  // ---- stage flow slab ----
  stage_slab(flow + (size_t)b * C_ * HW_ + (size_t)h * W_, ldsT, t);
  __syncthreads();

  // ---- K ----
  proj64(ldsT, Wk, bk, Kws, b, h, wv, col, lg);

  // ---- V: wave wv owns c-tiles [4wv, 4wv+4); output layout [b][w][g>>3][c][g&7] ----
  {
    f32x4 zero = {0.f, 0.f, 0.f, 0.f};
    f32x4 acc[4][8];
#pragma unroll
    for (int j = 0; j < 4; ++j)
#pragma unroll
      for (int i = 0; i < 8; ++i) acc[j][i] = zero;
#pragma unroll
    for (int ks = 0; ks < 8; ++ks) {
      half8 bfr[4];
#pragma unroll
      for (int j = 0; j < 4; ++j)
        bfr[j] = wfrag(Wv, (wv * 4 + j) * 16 + col, ks, lg);
#pragma unroll
      for (int wt = 0; wt < 8; ++wt) {
        const half8 afr = *afrag(ldsT, wt * 16 + col, ks, lg);
#pragma unroll
        for (int j = 0; j < 4; ++j)
          acc[j][wt] =
              __builtin_amdgcn_mfma_f32_16x16x32_f16(afr, bfr[j], acc[j][wt], 0, 0, 0);
      }
    }
#pragma unroll
    for (int j = 0; j < 4; ++j) {
      const int co = (wv * 4 + j) * 16 + col;
      const float bias = bv[co];
#pragma unroll
      for (int wt = 0; wt < 8; ++wt)
#pragma unroll
        for (int r = 0; r < 4; ++r) {
          int w = wt * 16 + lg * 4 + r;
          Vws[(size_t)(b * W_ + w) * 32768 + ((h >> 3) * COUT_ + co) * 8 + (h & 7)] =
              f16_rn(acc[j][wt][r] + bias);
        }
    }
  }
  __syncthreads();

  // ---- stage de_out slab ----
  stage_slab(de_out + (size_t)b * C_ * HW_ + (size_t)h * W_, ldsT, t);
  __syncthreads();

  // ---- Q ----
  proj64(ldsT, Wq, bq, Qws, b, h, wv, col, lg);
}

// ---------------------------------------------------------------------------
// Kernel 2: per-(b,w)-column attention.
// LDS = Q[128][72] + K[128][72] = 36.9 KB only; P overlays Q/K after E.
// V is read as PV B-fragments DIRECTLY from global (fragment-native layout,
// one dwordx4 per fragment; shared across waves via L2).
// ---------------------------------------------------------------------------
__global__ void __launch_bounds__(256) attn_kernel(
    const u16* __restrict__ Qws, const u16* __restrict__ Kws,
    const u16* __restrict__ Vws, float* __restrict__ out) {
  __shared__ __align__(16) u16 ldsQK[2 * 128 * QK_S];  // P (4*32*136=17408) overlays

  const int t   = threadIdx.x;
  const int bid = blockIdx.x;
  const int sw  = (bid & 7) * 256 + (bid >> 3);  // bijective
  const int b   = sw >> 7;
  const int w   = sw & 127;
  const int lane = t & 63;
  const int wv   = t >> 6;
  const int col  = lane & 15;
  const int lg   = lane >> 4;

  const u16* qc    = Qws + ((size_t)b * W_ + w) * H_ * C4_;
  const u16* kc    = Kws + ((size_t)b * W_ + w) * H_ * C4_;
  const u16* vbase = Vws + (size_t)(b * W_ + w) * 32768;

  u16* ldsQ = ldsQK;
  u16* ldsK = ldsQK + 128 * QK_S;

  // ---- stage Q, K: dwordx4 loads -> b128 LDS writes ----
#pragma unroll
  for (int i = 0; i < 4; ++i) {
    int item = i * 256 + t;
    int hh   = item >> 3;
    int d0   = (item & 7) * 8;
    *reinterpret_cast<half8*>(&ldsQ[hh * QK_S + d0]) =
        *reinterpret_cast<const half8*>(qc + item * 8);
    *reinterpret_cast<half8*>(&ldsK[hh * QK_S + d0]) =
        *reinterpret_cast<const half8*>(kc + item * 8);
  }
  __syncthreads();

  // ---- E = Q K^T for rows [wv*32, wv*32+32), all 128 g ----
  f32x4 zero = {0.f, 0.f, 0.f, 0.f};
  f32x4 e[2][8];
#pragma unroll
  for (int ht = 0; ht < 2; ++ht)
#pragma unroll
    for (int gt = 0; gt < 8; ++gt) e[ht][gt] = zero;

#pragma unroll
  for (int ks = 0; ks < 2; ++ks) {
    half8 aq[2];
#pragma unroll
    for (int ht = 0; ht < 2; ++ht)
      aq[ht] = *reinterpret_cast<const half8*>(
          &ldsQ[(wv * 32 + ht * 16 + col) * QK_S + ks * 32 + lg * 8]);
#pragma unroll
    for (int gt = 0; gt < 8; ++gt) {
      const half8 bk_ = *reinterpret_cast<const half8*>(
          &ldsK[(gt * 16 + col) * QK_S + ks * 32 + lg * 8]);
#pragma unroll
      for (int ht = 0; ht < 2; ++ht)
        e[ht][gt] = __builtin_amdgcn_mfma_f32_16x16x32_f16(aq[ht], bk_, e[ht][gt], 0, 0, 0);
    }
  }
  __syncthreads();  // Q/K dead -> region becomes P

  u16* ldsP = ldsQK + wv * 32 * P_S;  // wave-private slice

  // ---- softmax over g; row (lg*4+r) lives in the 16 lanes of group lg ----
#pragma unroll
  for (int ht = 0; ht < 2; ++ht)
#pragma unroll
    for (int r = 0; r < 4; ++r) {
      float m = -1e30f;
#pragma unroll
      for (int gt = 0; gt < 8; ++gt) m = fmaxf(m, e[ht][gt][r]);
#pragma unroll
      for (int off = 1; off < 16; off <<= 1) m = fmaxf(m, __shfl_xor(m, off));
      float s = 0.f;
#pragma unroll
      for (int gt = 0; gt < 8; ++gt) {
        float p = __expf(e[ht][gt][r] - m);
        e[ht][gt][r] = p;
        s += p;
      }
#pragma unroll
      for (int off = 1; off < 16; off <<= 1) s += __shfl_xor(s, off);
      const float inv = 1.f / s;
      const int hh = ht * 16 + lg * 4 + r;  // row within wave's 32
#pragma unroll
      for (int gt = 0; gt < 8; ++gt)
        ldsP[hh * P_S + gt * 16 + col] = f16_rn(e[ht][gt][r] * inv);
    }
  // ldsP slice is wave-private: in-wave ds ordering suffices.

  // ---- O = P V : rows [wv*32,+32) x 256 c; V fragments straight from global ----
  f32x4 o[2][16];
#pragma unroll
  for (int ht = 0; ht < 2; ++ht)
#pragma unroll
    for (int ct = 0; ct < 16; ++ct) o[ht][ct] = zero;

#pragma unroll
  for (int ks = 0; ks < 4; ++ks) {
    half8 ap[2];
#pragma unroll
    for (int ht = 0; ht < 2; ++ht)
      ap[ht] = *reinterpret_cast<const half8*>(
          &ldsP[(ht * 16 + col) * P_S + ks * 32 + lg * 8]);
#pragma unroll
    for (int ct = 0; ct < 16; ++ct) {
      const half8 bv_ = *reinterpret_cast<const half8*>(
          vbase + ((ks * 4 + lg) * COUT_ + ct * 16 + col) * 8);
#pragma unroll
      for (int ht = 0; ht < 2; ++ht)
        o[ht][ct] = __builtin_amdgcn_mfma_f32_16x16x32_f16(ap[ht], bv_, o[ht][ct], 0, 0, 0);
    }
  }

  // ---- epilogue: out[b, c, h, w] (fp32) ----
  float* outp = out + (size_t)b * COUT_ * HW_ + w;
#pragma unroll
  for (int ht = 0; ht < 2; ++ht)
#pragma unroll
    for (int ct = 0; ct < 16; ++ct)
#pragma unroll
      for (int r = 0; r < 4; ++r) {
        int hrow = wv * 32 + ht * 16 + lg * 4 + r;
        int c = ct * 16 + col;
        outp[((size_t)c * H_ + hrow) * W_] = o[ht][ct][r];
      }
}

extern "C" void kernel_launch(void* const* d_in, const int* in_sizes, int n_in,
                              void* d_out, int out_size, void* d_ws, size_t ws_size,
                              hipStream_t stream) {
  const float* flow   = (const float*)d_in[0];
  const float* de_out = (const float*)d_in[1];
  const float* Wq = (const float*)d_in[2];
  const float* bq = (const float*)d_in[3];
  const float* Wk = (const float*)d_in[4];
  const float* bk = (const float*)d_in[5];
  const float* Wv = (const float*)d_in[6];
  const float* bv = (const float*)d_in[7];
  float* out = (float*)d_out;

  u16* Qws = (u16*)d_ws;                                   // [b][w][h][d]      fp16
  u16* Kws = Qws + (size_t)B_ * W_ * H_ * C4_;             // [b][w][h][d]      fp16
  u16* Vws = Kws + (size_t)B_ * W_ * H_ * C4_;             // [b][w][g>>3][c][g&7] fp16
  // total ws use: 201,326,592 bytes

  qkv_kernel<<<B_ * H_, 256, 0, stream>>>(flow, de_out, Wq, bq, Wk, bk, Wv, bv,
                                          Qws, Kws, Vws);
  attn_kernel<<<B_ * W_, 256, 0, stream>>>(Qws, Kws, Vws, out);
}

// Round 4
// 630.417 us; speedup vs baseline: 1.2746x; 1.2746x over previous
//
#include <hip/hip_runtime.h>
#include <cstdint>
#include <cstddef>

typedef unsigned short u16;
using half4 = __attribute__((ext_vector_type(4))) _Float16;
using half8 = __attribute__((ext_vector_type(8))) _Float16;
using f32x4 = __attribute__((ext_vector_type(4))) float;
using f4    = __attribute__((ext_vector_type(4))) float;

#define B_    16
#define C_    256
#define H_    128
#define W_    128
#define C4_   64
#define COUT_ 256
#define HW_   (H_ * W_)

#define LDS_S1    264   // kernel1 slab [w][c]: 256 + 8 pad (octet-swizzled columns)
#define QK_S      72    // kernel2 Q/K [h][d]: 64 + 8 pad
#define P_S       136   // kernel2 P   [h][g]: 128 + 8 pad
#define XP_S      140   // kernel2 epilogue transpose tile [c][h]: 128 + 12 (16 distinct banks)

#define Q_ELEMS   ((size_t)B_ * W_ * H_ * C4_)      // 16,777,216
#define V_ELEMS   ((size_t)B_ * W_ * H_ * COUT_)    // 67,108,864
#define WS_NEED   (2 * Q_ELEMS * 2 + 2 * V_ELEMS * 2)  // Q+K+V+out_tmp fp16 = 335,544,320 B

__device__ __forceinline__ u16 f16_rn(float f) {
  _Float16 h = (_Float16)f;   // RN
  return __builtin_bit_cast(u16, h);
}

// ---------------------------------------------------------------------------
// Kernel 1: Q/K/V 1x1-conv projections (fp16 operands, fp32 accum).
// ---------------------------------------------------------------------------
__device__ __forceinline__ void stage_slab(const float* __restrict__ src,
                                           u16* __restrict__ ldsT, int t) {
#pragma unroll 4
  for (int i = 0; i < 16; ++i) {
    int u  = i * 256 + t;
    int p  = u >> 5;            // c-pair index 0..127
    int w4 = (u & 31) * 4;
    const float* s0 = src + (size_t)(2 * p) * HW_ + w4;
    f4 va = *reinterpret_cast<const f4*>(s0);
    f4 vb = *reinterpret_cast<const f4*>(s0 + HW_);
    const int c = 2 * p;
#pragma unroll
    for (int j = 0; j < 4; ++j) {
      int w   = w4 + j;
      int oct = (c >> 3) ^ ((w >> 2) & 7);
      uint32_t pk = (uint32_t)f16_rn(va[j]) | ((uint32_t)f16_rn(vb[j]) << 16);
      *reinterpret_cast<uint32_t*>(&ldsT[w * LDS_S1 + oct * 8 + (c & 7)]) = pk;
    }
  }
}

__device__ __forceinline__ const half8* afrag(const u16* __restrict__ ldsT,
                                              int w16, int ks, int lg) {
  int oct = (ks * 4 + lg) ^ ((w16 >> 2) & 7);
  return reinterpret_cast<const half8*>(&ldsT[w16 * LDS_S1 + oct * 8]);
}

__device__ __forceinline__ half8 wfrag(const float* __restrict__ Wm,
                                       int row, int ks, int lg) {
  const f4* wp = reinterpret_cast<const f4*>(Wm + (size_t)row * C_ + ks * 32 + lg * 8);
  f4 a = wp[0], b = wp[1];
  half8 r;
#pragma unroll
  for (int i = 0; i < 4; ++i) { r[i] = (_Float16)a[i]; r[4 + i] = (_Float16)b[i]; }
  return r;
}

__device__ __forceinline__ void proj64(const u16* __restrict__ ldsT,
                                       const float* __restrict__ Wm,
                                       const float* __restrict__ bm,
                                       u16* __restrict__ dst,
                                       int b, int h, int wv, int col, int lg) {
  f32x4 zero = {0.f, 0.f, 0.f, 0.f};
  f32x4 acc[8];
#pragma unroll
  for (int i = 0; i < 8; ++i) acc[i] = zero;
#pragma unroll
  for (int ks = 0; ks < 8; ++ks) {
    half8 bfr = wfrag(Wm, wv * 16 + col, ks, lg);
#pragma unroll
    for (int wt = 0; wt < 8; ++wt) {
      const half8 afr = *afrag(ldsT, wt * 16 + col, ks, lg);
      acc[wt] = __builtin_amdgcn_mfma_f32_16x16x32_f16(afr, bfr, acc[wt], 0, 0, 0);
    }
  }
  const float bias = bm[wv * 16 + col];
#pragma unroll
  for (int wt = 0; wt < 8; ++wt)
#pragma unroll
    for (int r = 0; r < 4; ++r) {
      int w = wt * 16 + lg * 4 + r;
      dst[(((size_t)b * W_ + w) * H_ + h) * C4_ + wv * 16 + col] =
          f16_rn(acc[wt][r] + bias);
    }
}

__global__ void __launch_bounds__(256) qkv_kernel(
    const float* __restrict__ flow, const float* __restrict__ de_out,
    const float* __restrict__ Wq, const float* __restrict__ bq,
    const float* __restrict__ Wk, const float* __restrict__ bk,
    const float* __restrict__ Wv, const float* __restrict__ bv,
    u16* __restrict__ Qws, u16* __restrict__ Kws, u16* __restrict__ Vws) {
  __shared__ __align__(16) u16 ldsT[128 * LDS_S1];
  const int t    = threadIdx.x;
  const int bid  = blockIdx.x;
  const int sw   = (bid & 7) * 256 + (bid >> 3);  // bijective (2048 % 8 == 0)
  const int b    = sw >> 7;
  const int h    = sw & 127;
  const int lane = t & 63;
  const int wv   = t >> 6;
  const int col  = lane & 15;
  const int lg   = lane >> 4;

  stage_slab(flow + (size_t)b * C_ * HW_ + (size_t)h * W_, ldsT, t);
  __syncthreads();

  proj64(ldsT, Wk, bk, Kws, b, h, wv, col, lg);

  // ---- V: wave wv owns c-tiles [4wv, 4wv+4); output layout [b][w][g>>3][c][g&7] ----
  {
    f32x4 zero = {0.f, 0.f, 0.f, 0.f};
    f32x4 acc[4][8];
#pragma unroll
    for (int j = 0; j < 4; ++j)
#pragma unroll
      for (int i = 0; i < 8; ++i) acc[j][i] = zero;
#pragma unroll
    for (int ks = 0; ks < 8; ++ks) {
      half8 bfr[4];
#pragma unroll
      for (int j = 0; j < 4; ++j)
        bfr[j] = wfrag(Wv, (wv * 4 + j) * 16 + col, ks, lg);
#pragma unroll
      for (int wt = 0; wt < 8; ++wt) {
        const half8 afr = *afrag(ldsT, wt * 16 + col, ks, lg);
#pragma unroll
        for (int j = 0; j < 4; ++j)
          acc[j][wt] =
              __builtin_amdgcn_mfma_f32_16x16x32_f16(afr, bfr[j], acc[j][wt], 0, 0, 0);
      }
    }
#pragma unroll
    for (int j = 0; j < 4; ++j) {
      const int co = (wv * 4 + j) * 16 + col;
      const float bias = bv[co];
#pragma unroll
      for (int wt = 0; wt < 8; ++wt)
#pragma unroll
        for (int r = 0; r < 4; ++r) {
          int w = wt * 16 + lg * 4 + r;
          Vws[(size_t)(b * W_ + w) * 32768 + ((h >> 3) * COUT_ + co) * 8 + (h & 7)] =
              f16_rn(acc[j][wt][r] + bias);
        }
    }
  }
  __syncthreads();

  stage_slab(de_out + (size_t)b * C_ * HW_ + (size_t)h * W_, ldsT, t);
  __syncthreads();

  proj64(ldsT, Wq, bq, Qws, b, h, wv, col, lg);
}

// ---------------------------------------------------------------------------
// Kernel 2: per-(b,w)-column attention.
// EPI=1: epilogue transposes o through LDS and stores fp16 out_tmp[b][w][c][h]
//        fully coalesced (transpose to [b][c][h][w] done by kernel 3).
// EPI=0: legacy direct fp32 scatter (fallback if ws too small).
// ---------------------------------------------------------------------------
template <int EPI>
__global__ void __launch_bounds__(256) attn_kernel(
    const u16* __restrict__ Qws, const u16* __restrict__ Kws,
    const u16* __restrict__ Vws, u16* __restrict__ out_tmp,
    float* __restrict__ out) {
  __shared__ __align__(16) u16 ldsQK[2 * 128 * QK_S];  // P and epi-tile overlay

  const int t   = threadIdx.x;
  const int bid = blockIdx.x;
  const int sw  = (bid & 7) * 256 + (bid >> 3);  // bijective
  const int b   = sw >> 7;
  const int w   = sw & 127;
  const int lane = t & 63;
  const int wv   = t >> 6;
  const int col  = lane & 15;
  const int lg   = lane >> 4;

  const u16* qc    = Qws + ((size_t)b * W_ + w) * H_ * C4_;
  const u16* kc    = Kws + ((size_t)b * W_ + w) * H_ * C4_;
  const u16* vbase = Vws + (size_t)(b * W_ + w) * 32768;

  u16* ldsQ = ldsQK;
  u16* ldsK = ldsQK + 128 * QK_S;

  // ---- stage Q, K: dwordx4 loads -> b128 LDS writes ----
#pragma unroll
  for (int i = 0; i < 4; ++i) {
    int item = i * 256 + t;
    int hh   = item >> 3;
    int d0   = (item & 7) * 8;
    *reinterpret_cast<half8*>(&ldsQ[hh * QK_S + d0]) =
        *reinterpret_cast<const half8*>(qc + item * 8);
    *reinterpret_cast<half8*>(&ldsK[hh * QK_S + d0]) =
        *reinterpret_cast<const half8*>(kc + item * 8);
  }
  __syncthreads();

  // ---- E = Q K^T for rows [wv*32, wv*32+32), all 128 g ----
  f32x4 zero = {0.f, 0.f, 0.f, 0.f};
  f32x4 e[2][8];
#pragma unroll
  for (int ht = 0; ht < 2; ++ht)
#pragma unroll
    for (int gt = 0; gt < 8; ++gt) e[ht][gt] = zero;

#pragma unroll
  for (int ks = 0; ks < 2; ++ks) {
    half8 aq[2];
#pragma unroll
    for (int ht = 0; ht < 2; ++ht)
      aq[ht] = *reinterpret_cast<const half8*>(
          &ldsQ[(wv * 32 + ht * 16 + col) * QK_S + ks * 32 + lg * 8]);
#pragma unroll
    for (int gt = 0; gt < 8; ++gt) {
      const half8 bk_ = *reinterpret_cast<const half8*>(
          &ldsK[(gt * 16 + col) * QK_S + ks * 32 + lg * 8]);
#pragma unroll
      for (int ht = 0; ht < 2; ++ht)
        e[ht][gt] = __builtin_amdgcn_mfma_f32_16x16x32_f16(aq[ht], bk_, e[ht][gt], 0, 0, 0);
    }
  }
  __syncthreads();  // Q/K dead -> region becomes P

  u16* ldsP = ldsQK + wv * 32 * P_S;  // wave-private slice

  // ---- softmax over g ----
#pragma unroll
  for (int ht = 0; ht < 2; ++ht)
#pragma unroll
    for (int r = 0; r < 4; ++r) {
      float m = -1e30f;
#pragma unroll
      for (int gt = 0; gt < 8; ++gt) m = fmaxf(m, e[ht][gt][r]);
#pragma unroll
      for (int off = 1; off < 16; off <<= 1) m = fmaxf(m, __shfl_xor(m, off));
      float s = 0.f;
#pragma unroll
      for (int gt = 0; gt < 8; ++gt) {
        float p = __expf(e[ht][gt][r] - m);
        e[ht][gt][r] = p;
        s += p;
      }
#pragma unroll
      for (int off = 1; off < 16; off <<= 1) s += __shfl_xor(s, off);
      const float inv = 1.f / s;
      const int hh = ht * 16 + lg * 4 + r;
#pragma unroll
      for (int gt = 0; gt < 8; ++gt)
        ldsP[hh * P_S + gt * 16 + col] = f16_rn(e[ht][gt][r] * inv);
    }

  // ---- O = P V : rows [wv*32,+32) x 256 c; V fragments straight from global ----
  f32x4 o[2][16];
#pragma unroll
  for (int ht = 0; ht < 2; ++ht)
#pragma unroll
    for (int ct = 0; ct < 16; ++ct) o[ht][ct] = zero;

#pragma unroll
  for (int ks = 0; ks < 4; ++ks) {
    half8 ap[2];
#pragma unroll
    for (int ht = 0; ht < 2; ++ht)
      ap[ht] = *reinterpret_cast<const half8*>(
          &ldsP[(ht * 16 + col) * P_S + ks * 32 + lg * 8]);
#pragma unroll
    for (int ct = 0; ct < 16; ++ct) {
      const half8 bv_ = *reinterpret_cast<const half8*>(
          vbase + ((ks * 4 + lg) * COUT_ + ct * 16 + col) * 8);
#pragma unroll
      for (int ht = 0; ht < 2; ++ht)
        o[ht][ct] = __builtin_amdgcn_mfma_f32_16x16x32_f16(ap[ht], bv_, o[ht][ct], 0, 0, 0);
    }
  }

  if (EPI == 1) {
    // ---- epilogue A: LDS-transpose 64c x 128h tiles -> fp16 out_tmp[b][w][c][h] ----
    u16* ldsX = ldsQK;  // reuse (17,920 B of 36,864)
    u16* dst_col = out_tmp + ((size_t)(b * W_ + w) << 15);
#pragma unroll
    for (int ctg = 0; ctg < 4; ++ctg) {
      __syncthreads();  // P dead (first iter) / previous tile consumed
#pragma unroll
      for (int j = 0; j < 4; ++j) {
        const int ct    = ctg * 4 + j;
        const int c_loc = j * 16 + col;
#pragma unroll
        for (int ht = 0; ht < 2; ++ht) {
          const int hbase = wv * 32 + ht * 16 + lg * 4;
          half4 pk;
#pragma unroll
          for (int r = 0; r < 4; ++r) pk[r] = (_Float16)o[ht][ct][r];
          *reinterpret_cast<half4*>(&ldsX[c_loc * XP_S + hbase]) = pk;
        }
      }
      __syncthreads();
      const int c_loc = t >> 2;
      const int h0    = (t & 3) * 32;
      u16* dp = dst_col + (ctg * 64 + c_loc) * 128 + h0;
#pragma unroll
      for (int k = 0; k < 4; ++k)
        *reinterpret_cast<half8*>(dp + k * 8) =
            *reinterpret_cast<const half8*>(&ldsX[c_loc * XP_S + h0 + k * 8]);
    }
  } else {
    // ---- epilogue B (fallback): direct fp32 scatter ----
    float* outp = out + (size_t)b * COUT_ * HW_ + w;
#pragma unroll
    for (int ht = 0; ht < 2; ++ht)
#pragma unroll
      for (int ct = 0; ct < 16; ++ct)
#pragma unroll
        for (int r = 0; r < 4; ++r) {
          int hrow = wv * 32 + ht * 16 + lg * 4 + r;
          int c = ct * 16 + col;
          outp[((size_t)c * H_ + hrow) * W_] = o[ht][ct][r];
        }
  }
}

// ---------------------------------------------------------------------------
// Kernel 3: out_tmp[b][w][f] fp16 -> out[b][f][w] fp32   (f = c*128 + h)
// 64f x 128w LDS tile; both global sides fully coalesced.
// ---------------------------------------------------------------------------
__global__ void __launch_bounds__(256) transpose_kernel(
    const u16* __restrict__ T, float* __restrict__ out) {
  __shared__ float lds[64 * 132];
  const int t   = threadIdx.x;
  const int bid = blockIdx.x;
  const int b   = bid >> 9;
  const int ft  = bid & 511;  // f-tile of 64

  // load: thread reads 64 contiguous bytes of one (w, half-tile)
  {
    const int w  = t >> 1;
    const int fo = (t & 1) * 32;
    const u16* src = T + ((size_t)(b * W_ + w) << 15) + ft * 64 + fo;
#pragma unroll
    for (int k = 0; k < 4; ++k) {
      half8 v = *reinterpret_cast<const half8*>(src + k * 8);
#pragma unroll
      for (int e = 0; e < 8; ++e)
        lds[(fo + k * 8 + e) * 132 + w] = (float)v[e];
    }
  }
  __syncthreads();
  {
    const int f_loc = t >> 2;
    const int w0    = (t & 3) * 32;
    float* dst = out + (size_t)b * (COUT_ * HW_) + (size_t)(ft * 64 + f_loc) * 128 + w0;
#pragma unroll
    for (int k = 0; k < 8; ++k) {
      f4 v4;
#pragma unroll
      for (int e = 0; e < 4; ++e) v4[e] = lds[f_loc * 132 + w0 + k * 4 + e];
      *reinterpret_cast<f4*>(dst + k * 4) = v4;
    }
  }
}

extern "C" void kernel_launch(void* const* d_in, const int* in_sizes, int n_in,
                              void* d_out, int out_size, void* d_ws, size_t ws_size,
                              hipStream_t stream) {
  const float* flow   = (const float*)d_in[0];
  const float* de_out = (const float*)d_in[1];
  const float* Wq = (const float*)d_in[2];
  const float* bq = (const float*)d_in[3];
  const float* Wk = (const float*)d_in[4];
  const float* bk = (const float*)d_in[5];
  const float* Wv = (const float*)d_in[6];
  const float* bv = (const float*)d_in[7];
  float* out = (float*)d_out;

  u16* Qws = (u16*)d_ws;                 // [b][w][h][d]            fp16
  u16* Kws = Qws + Q_ELEMS;              // [b][w][h][d]            fp16
  u16* Vws = Kws + Q_ELEMS;              // [b][w][g>>3][c][g&7]    fp16
  u16* Tws = Vws + V_ELEMS;              // [b][w][c][h]            fp16

  qkv_kernel<<<B_ * H_, 256, 0, stream>>>(flow, de_out, Wq, bq, Wk, bk, Wv, bv,
                                          Qws, Kws, Vws);
  if (ws_size >= (size_t)WS_NEED) {
    attn_kernel<1><<<B_ * W_, 256, 0, stream>>>(Qws, Kws, Vws, Tws, out);
    transpose_kernel<<<B_ * 512, 256, 0, stream>>>(Tws, out);
  } else {
    attn_kernel<0><<<B_ * W_, 256, 0, stream>>>(Qws, Kws, Vws, Tws, out);
  }
}